// Round 8
// baseline (1091.210 us; speedup 1.0000x reference)
//
#include <hip/hip_runtime.h>

typedef unsigned int u32;
typedef unsigned short u16;
typedef __attribute__((ext_vector_type(8))) __bf16 bf16x8;
typedef __attribute__((ext_vector_type(4))) float f32x4;

typedef __attribute__((address_space(1))) void as1_void;
typedef __attribute__((address_space(3))) void as3_void;

__device__ __forceinline__ u16 f2bf(float f){
  u32 u = __builtin_bit_cast(u32, f);
  return (u16)((u + 0x7FFFu + ((u >> 16) & 1u)) >> 16);
}
__device__ __forceinline__ float bf2f(u16 h){
  u32 u = ((u32)h) << 16;
  return __builtin_bit_cast(float, u);
}

__device__ __forceinline__ void gload16(const void* g, void* l){
  __builtin_amdgcn_global_load_lds((as1_void*)(unsigned long long)g, (as3_void*)l, 16, 0, 0);
}
__device__ __forceinline__ bf16x8 ldfrag(const char* p){
  return __builtin_bit_cast(bf16x8, *(const uint4*)p);
}
__device__ __forceinline__ uint4 cvt8(float4 a, float4 b){
  union { uint4 u; __bf16 h[8]; } uu;
  uu.h[0]=(__bf16)a.x; uu.h[1]=(__bf16)a.y; uu.h[2]=(__bf16)a.z; uu.h[3]=(__bf16)a.w;
  uu.h[4]=(__bf16)b.x; uu.h[5]=(__bf16)b.y; uu.h[6]=(__bf16)b.z; uu.h[7]=(__bf16)b.w;
  return uu.u;
}

// ---------- weight transpose-cast: out[n][k] = W[k][n] * scale (1024x1024) ----------
__global__ void wcast(const float* __restrict__ W, float scale, u16* __restrict__ out){
  __shared__ float t[32][33];
  int bx = blockIdx.x * 32, by = blockIdx.y * 32;
  int tx = threadIdx.x, ty = threadIdx.y;
  #pragma unroll
  for (int i = 0; i < 32; i += 8) t[ty + i][tx] = W[(size_t)(bx + ty + i) * 1024 + by + tx];
  __syncthreads();
  #pragma unroll
  for (int i = 0; i < 32; i += 8)
    out[(size_t)(by + ty + i) * 1024 + bx + tx] = f2bf(scale * t[tx][ty + i]);
}

// ---------- row softmax, in-place on bf16 S rows of length 2048 ----------
__global__ __launch_bounds__(256) void softmax_rows(u16* __restrict__ S){
  __shared__ float red[8];
  size_t row = blockIdx.x;
  uint4* p = (uint4*)(S + row * 2048);
  int tid = threadIdx.x;
  int lane = tid & 63, wave = tid >> 6;
  union { uint4 u4; u16 h[8]; } uu;
  uu.u4 = p[tid];
  float v[8];
  float m = -1e30f;
  #pragma unroll
  for (int j = 0; j < 8; j++){ v[j] = bf2f(uu.h[j]); m = fmaxf(m, v[j]); }
  #pragma unroll
  for (int o = 32; o; o >>= 1) m = fmaxf(m, __shfl_xor(m, o));
  if (lane == 0) red[wave] = m;
  __syncthreads();
  m = fmaxf(fmaxf(red[0], red[1]), fmaxf(red[2], red[3]));
  float s = 0.f;
  #pragma unroll
  for (int j = 0; j < 8; j++){ v[j] = __expf(v[j] - m); s += v[j]; }
  #pragma unroll
  for (int o = 32; o; o >>= 1) s += __shfl_xor(s, o);
  if (lane == 0) red[4 + wave] = s;
  __syncthreads();
  s = red[4] + red[5] + red[6] + red[7];
  float inv = 1.f / s;
  #pragma unroll
  for (int j = 0; j < 8; j++) uu.h[j] = f2bf(v[j] * inv);
  p[tid] = uu.u4;
}

// ---------- persistent 256x256 8-phase GEMM ----------
// C[M][N] = A[M][K] @ B[N][K]^T (+col bias). AF32/BF32: that operand is fp32 in
// global, reg-staged (float4 loads -> cvt -> swizzled ds_write). Pure-bf16 path
// keeps the R6 hoisted-read schedule + interleaved prologue (vmcnt(6) positional).

template<int MO, int N0>
__device__ __forceinline__ void pm(f32x4 (&acc)[8][4], bf16x8 (&a)[4][2], bf16x8 (&b)[2][2]){
  __builtin_amdgcn_s_setprio(1);
  #pragma unroll
  for (int ks = 0; ks < 2; ks++)
    #pragma unroll
    for (int mm = 0; mm < 4; mm++)
      #pragma unroll
      for (int nn = 0; nn < 2; nn++)
        acc[MO + mm][N0 + nn] = __builtin_amdgcn_mfma_f32_16x16x32_bf16(
            a[mm][ks], b[nn][ks], acc[MO + mm][N0 + nn], 0, 0, 0);
  __builtin_amdgcn_s_setprio(0);
}

template<int AF32, int BF32, int BIAS, int OUTF32>
__global__ __launch_bounds__(512, 2) void gemm8(
    const void* __restrict__ A, const void* __restrict__ B, void* __restrict__ C,
    const float* __restrict__ bias, float bscale, int NT,
    long long sA, long long sB, long long sC,
    int lda, int ldb, int ldc, int gx, int gxy, int TPB)
{
  constexpr bool HOIST = (!AF32 && !BF32);
  __shared__ u16 sm[2][2][16384];   // [buf][A/B] 128 KiB
  char* smb = (char*)sm;

  int tid = threadIdx.x;
  int lane = tid & 63, wave = tid >> 6;
  int wr = wave >> 2, wc = wave & 3;
  int l15 = lane & 15, l4 = lane >> 4;

  int b = blockIdx.x;
  int lin0 = ((b & 7) * 32 + (b >> 3)) * TPB;   // XCD-chunked tile range

  // staging addressing: quarter i covers rows [i*64, i*64+64), 16B LDS chunk per lane
  int r = tid >> 3, cl = tid & 7;
  int ldsb = r * 128 + cl * 16;                    // linear dest (gload path)
  int ldsw = r * 128 + ((cl ^ (r & 7)) * 16);      // swizzled dest (ds_write path)
  u32 aoff[4], boff[4];
  #pragma unroll
  for (int i = 0; i < 4; i++){
    int row = i * 64 + r;
    if constexpr (AF32) aoff[i] = (u32)(((u32)row * (u32)lda + (u32)(cl * 8)) * 4u);
    else                aoff[i] = (u32)(((u32)row * (u32)lda + (u32)((cl ^ (r & 7)) * 8)) * 2u);
    if constexpr (BF32) boff[i] = (u32)(((u32)row * (u32)ldb + (u32)(cl * 8)) * 4u);
    else                boff[i] = (u32)(((u32)row * (u32)ldb + (u32)((cl ^ (r & 7)) * 8)) * 2u);
  }
  // fragment-read addressing (swizzled)
  u32 ardo[2], brdo[2];
  #pragma unroll
  for (int ks = 0; ks < 2; ks++){
    u32 sw = (u32)(((ks * 4 + l4) ^ (l15 & 7)) * 16);
    ardo[ks] = (u32)(wr * 16384 + l15 * 128) + sw;
    brdo[ks] = (u32)(wc * 8192 + l15 * 128) + sw;
  }

  auto tcoord = [&](int lin, int& x, int& y, int& z){
    z = lin / gxy; int rem = lin - z * gxy; y = rem / gx; x = rem - y * gx;
  };
  auto abase = [&](int lin){ int x, y, z; tcoord(lin, x, y, z);
    return (const char*)A + ((long long)z * sA + (long long)(x * 256) * lda) * (AF32 ? 4 : 2); };
  auto bbase = [&](int lin){ int x, y, z; tcoord(lin, x, y, z);
    return (const char*)B + ((long long)z * sB + (long long)(y * 256) * ldb) * (BF32 ? 4 : 2); };

  int tx, ty, tz;
  tcoord(lin0, tx, ty, tz);
  int row0 = tx * 256, col0 = ty * 256;
  long long zbC = tz;

  // bias preload (col bias; all BIAS=1 calls have TPB<=2)
  float bc0[4], bc1[4];
  if (BIAS){
    int xx, yy, zz;
    tcoord(lin0, xx, yy, zz);
    int c0 = yy * 256 + wc * 64 + l15;
    #pragma unroll
    for (int n = 0; n < 4; n++) bc0[n] = bscale * bias[c0 + n * 16];
    tcoord(lin0 + (TPB > 1 ? 1 : 0), xx, yy, zz);
    c0 = yy * 256 + wc * 64 + l15;
    #pragma unroll
    for (int n = 0; n < 4; n++) bc1[n] = bscale * bias[c0 + n * 16];
  }

  // staging cursors: M -> tile of (s+1) [A_hi gload], P -> tile of (s+2)
  const char* AgM = abase(lin0);
  const char* AgP = AgM;
  const char* BgP = bbase(lin0);
  int km = 1, kp = 2, jm = 0, jp = 0, kk = 0, jj = 0;

#define STA(bse, i, kq, bb) gload16((bse) + aoff[i] + (size_t)(kq) * 128, smb + (bb) * 65536 + (i) * 8192 + ldsb)
#define STB(bse, i, kq, bb) gload16((bse) + boff[i] + (size_t)(kq) * 128, smb + (bb) * 65536 + 32768 + (i) * 8192 + ldsb)

  // ---- prologue: tiles 0 and 1 ----
  if constexpr (HOIST){
    // EXACT R6 issue order — vmcnt(6) below relies on it (in-order completion):
    // oldest 8 = tile0 A(q0,q2) + tile0 B(q0..q3) + tile0 A(q1,q3).
    STA(AgM, 0, 0, 0); STA(AgM, 2, 0, 0);
    STB(BgP, 0, 0, 0); STB(BgP, 1, 0, 0); STB(BgP, 2, 0, 0); STB(BgP, 3, 0, 0);
    STA(AgM, 1, 0, 0); STA(AgM, 3, 0, 0);
    STA(AgM, 0, 1, 1); STA(AgM, 2, 1, 1);
    STB(BgP, 0, 1, 1); STB(BgP, 1, 1, 1); STB(BgP, 2, 1, 1); STB(BgP, 3, 1, 1);
    asm volatile("s_waitcnt vmcnt(6)" ::: "memory");
  } else {
    if constexpr (!AF32){
      STA(AgM, 0, 0, 0); STA(AgM, 2, 0, 0); STA(AgM, 1, 0, 0); STA(AgM, 3, 0, 0);
      STA(AgM, 0, 1, 1); STA(AgM, 2, 1, 1);
    }
    if constexpr (!BF32){
      STB(BgP, 0, 0, 0); STB(BgP, 1, 0, 0); STB(BgP, 2, 0, 0); STB(BgP, 3, 0, 0);
      STB(BgP, 0, 1, 1); STB(BgP, 1, 1, 1); STB(BgP, 2, 1, 1); STB(BgP, 3, 1, 1);
    }
    if constexpr (AF32){
      #pragma unroll
      for (int t = 0; t < 2; t++){
        float4 x0[4], x1[4];
        #pragma unroll
        for (int i = 0; i < 4; i++){
          const float4* p = (const float4*)(AgP + aoff[i] + (u32)t * 256u);
          x0[i] = p[0]; x1[i] = p[1];
        }
        #pragma unroll
        for (int i = 0; i < 4; i++)
          *(uint4*)(smb + t * 65536 + i * 8192 + ldsw) = cvt8(x0[i], x1[i]);
      }
    }
    if constexpr (BF32){
      #pragma unroll
      for (int t = 0; t < 2; t++){
        float4 x0[4], x1[4];
        #pragma unroll
        for (int i = 0; i < 4; i++){
          const float4* p = (const float4*)(BgP + boff[i] + (u32)t * 256u);
          x0[i] = p[0]; x1[i] = p[1];
        }
        #pragma unroll
        for (int i = 0; i < 4; i++)
          *(uint4*)(smb + t * 65536 + 32768 + i * 8192 + ldsw) = cvt8(x0[i], x1[i]);
      }
    }
    asm volatile("s_waitcnt vmcnt(0) lgkmcnt(0)" ::: "memory");
  }
  __builtin_amdgcn_s_barrier();

  f32x4 acc[8][4] = {};
  bf16x8 aLo[4][2], aHi[4][2], b01[2][2], b23[2][2];
  float4 av0[4], av1[4], bv0[4], bv1[4];
  int S = TPB * NT;

  if constexpr (HOIST){
    // initial aLo(0) from buffer 0
    #pragma unroll
    for (int mm = 0; mm < 4; mm++)
      #pragma unroll
      for (int ks = 0; ks < 2; ks++)
        aLo[mm][ks] = ldfrag(smb + mm * 2048 + ardo[ks]);
  }

  for (int s = 0; s < S; s++){
    int cur = s & 1;
    const char* Ab = smb + cur * 65536;
    const char* Bb = Ab + 32768;
    const char* AbN = smb + (cur ^ 1) * 65536;
    bool st1 = (s + 1 < S), st2 = (s + 2 < S);

    // ---- P0 ----
    if constexpr (AF32){
      if (st2){
        #pragma unroll
        for (int i = 0; i < 4; i++){
          const float4* p = (const float4*)(AgP + aoff[i] + (u32)kp * 256u);
          av0[i] = p[0]; av1[i] = p[1];
        }
      }
    } else {
      if (st1){ STA(AgM, 1, km, cur ^ 1); STA(AgM, 3, km, cur ^ 1); }
    }
    if constexpr (BF32){
      if (st2){
        #pragma unroll
        for (int i = 0; i < 4; i++){
          const float4* p = (const float4*)(BgP + boff[i] + (u32)kp * 256u);
          bv0[i] = p[0]; bv1[i] = p[1];
        }
      }
    }
    if constexpr (!HOIST){
      #pragma unroll
      for (int mm = 0; mm < 4; mm++)
        #pragma unroll
        for (int ks = 0; ks < 2; ks++)
          aLo[mm][ks] = ldfrag(Ab + mm * 2048 + ardo[ks]);
    }
    #pragma unroll
    for (int nn = 0; nn < 2; nn++)
      #pragma unroll
      for (int ks = 0; ks < 2; ks++)
        b01[nn][ks] = ldfrag(Bb + nn * 2048 + brdo[ks]);
    #pragma unroll
    for (int nn = 0; nn < 2; nn++)
      #pragma unroll
      for (int ks = 0; ks < 2; ks++)
        b23[nn][ks] = ldfrag(Bb + (2 + nn) * 2048 + brdo[ks]);
    __builtin_amdgcn_s_barrier();
    pm<0, 0>(acc, aLo, b01);
    __builtin_amdgcn_s_barrier();

    // ---- P1 ----
    if constexpr (!AF32){
      if (st2){ STA(AgP, 0, kp, cur); STA(AgP, 2, kp, cur); }
    }
    if constexpr (HOIST){
      #pragma unroll
      for (int mm = 0; mm < 4; mm++)
        #pragma unroll
        for (int ks = 0; ks < 2; ks++)
          aHi[mm][ks] = ldfrag(Ab + (4 + mm) * 2048 + ardo[ks]);
    }
    __builtin_amdgcn_s_barrier();
    pm<0, 2>(acc, aLo, b23);
    __builtin_amdgcn_s_barrier();

    // ---- P2 ----
    if constexpr (BF32){
      if (st2){
        char* W = smb + cur * 65536 + 32768;
        #pragma unroll
        for (int i = 0; i < 4; i++)
          *(uint4*)(W + i * 8192 + ldsw) = cvt8(bv0[i], bv1[i]);
      }
    } else {
      if (st2){ STB(BgP, 0, kp, cur); STB(BgP, 1, kp, cur); }
    }
    if constexpr (!HOIST){
      #pragma unroll
      for (int mm = 0; mm < 4; mm++)
        #pragma unroll
        for (int ks = 0; ks < 2; ks++)
          aHi[mm][ks] = ldfrag(Ab + (4 + mm) * 2048 + ardo[ks]);
    }
    __builtin_amdgcn_s_barrier();
    pm<4, 2>(acc, aHi, b23);
    __builtin_amdgcn_s_barrier();

    // ---- P3 ----
    if constexpr (!BF32){
      if (st2){ STB(BgP, 2, kp, cur); STB(BgP, 3, kp, cur); }
    }
    if constexpr (AF32){
      if (st2){
        char* W = smb + cur * 65536;
        #pragma unroll
        for (int i = 0; i < 4; i++)
          *(uint4*)(W + i * 8192 + ldsw) = cvt8(av0[i], av1[i]);
      }
    }
    {
      constexpr int VN = AF32 ? 4 : (BF32 ? 2 : 6);
      if (s < S - 2){
        if constexpr (VN == 4) asm volatile("s_waitcnt vmcnt(4)" ::: "memory");
        else if constexpr (VN == 2) asm volatile("s_waitcnt vmcnt(2)" ::: "memory");
        else asm volatile("s_waitcnt vmcnt(6)" ::: "memory");
      } else {
        asm volatile("s_waitcnt vmcnt(0)" ::: "memory");
      }
    }
    __builtin_amdgcn_s_barrier();
    if constexpr (HOIST){
      if (st1){
        #pragma unroll
        for (int mm = 0; mm < 4; mm++)
          #pragma unroll
          for (int ks = 0; ks < 2; ks++)
            aLo[mm][ks] = ldfrag(AbN + mm * 2048 + ardo[ks]);
      }
    }
    pm<4, 0>(acc, aHi, b01);
    __builtin_amdgcn_s_barrier();

    // ---- cursor advance + epilogue at tile boundary ----
    if constexpr (!AF32){
      if (++km == NT){ km = 0; if (++jm < TPB) AgM = abase(lin0 + jm); }
    }
    if (++kp == NT){ kp = 0; if (++jp < TPB){ AgP = abase(lin0 + jp); BgP = bbase(lin0 + jp); } }
    if (++kk == NT){
      kk = 0;
      #pragma unroll
      for (int m = 0; m < 8; m++){
        #pragma unroll
        for (int n = 0; n < 4; n++){
          int gr0 = row0 + wr * 128 + m * 16 + l4 * 4;
          int gc  = col0 + wc * 64 + n * 16 + l15;
          float bcol = BIAS ? (jj == 0 ? bc0[n] : bc1[n]) : 0.f;
          #pragma unroll
          for (int j = 0; j < 4; j++){
            float vv = acc[m][n][j] + bcol;
            int gr = gr0 + j;
            if (OUTF32) ((float*)C)[zbC * sC + (size_t)gr * ldc + gc] = vv;
            else        ((u16*) C)[zbC * sC + (size_t)gr * ldc + gc] = f2bf(vv);
          }
          acc[m][n] = (f32x4){0.f, 0.f, 0.f, 0.f};
        }
      }
      if (++jj < TPB){
        tcoord(lin0 + jj, tx, ty, tz);
        row0 = tx * 256; col0 = ty * 256; zbC = tz;
      }
    }
  }
#undef STA
#undef STB
}

extern "C" void kernel_launch(void* const* d_in, const int* in_sizes, int n_in,
                              void* d_out, int out_size, void* d_ws, size_t ws_size,
                              hipStream_t stream){
  const float* q  = (const float*)d_in[0];
  const float* k  = (const float*)d_in[1];
  const float* v  = (const float*)d_in[2];
  const float* Wq = (const float*)d_in[3];
  const float* bq = (const float*)d_in[4];
  const float* Wk = (const float*)d_in[5];
  const float* bk = (const float*)d_in[6];
  const float* Wv = (const float*)d_in[7];
  const float* bv = (const float*)d_in[8];
  const float* Wo = (const float*)d_in[9];
  const float* bo = (const float*)d_in[10];

  char* ws = (char*)d_ws;
  const size_t MB = (size_t)1 << 20;
  u16* Wqt = (u16*)(ws + 0 * MB);
  u16* Wkt = (u16*)(ws + 2 * MB);
  u16* Wvt = (u16*)(ws + 4 * MB);
  u16* Wot = (u16*)(ws + 6 * MB);
  u16* Qp  = (u16*)(ws + 8 * MB);    // [32768][1024] bf16
  u16* Kp  = (u16*)(ws + 72 * MB);   // [32768][1024] bf16
  u16* Vt  = (u16*)(ws + 136 * MB);  // [16][1024][2048] bf16
  u16* S   = (u16*)(ws + 200 * MB);  // [16][2048][2048] bf16 (P in-place)
  u16* O   = (u16*)(ws + 328 * MB);  // [32768][1024] bf16
  float* out = (float*)d_out;

  dim3 wb(32, 8);
  wcast<<<dim3(32, 32), wb, 0, stream>>>(Wq, 1.f / 32.f, Wqt);  // fold 1/sqrt(D)
  wcast<<<dim3(32, 32), wb, 0, stream>>>(Wk, 1.f, Wkt);
  wcast<<<dim3(32, 32), wb, 0, stream>>>(Wv, 1.f, Wvt);
  wcast<<<dim3(32, 32), wb, 0, stream>>>(Wo, 1.f, Wot);

  // Q' = (q @ Wq + bq)/32   (A = q fp32, reg-staged)
  gemm8<1,0,1,0><<<dim3(256), 512, 0, stream>>>(q, Wqt, Qp, bq, 1.f/32.f,
      16, 0, 0, 0, 1024, 1024, 1024, 128, 512, 2);
  // K' = k @ Wk + bk
  gemm8<1,0,1,0><<<dim3(256), 512, 0, stream>>>(k, Wkt, Kp, bk, 1.f,
      16, 0, 0, 0, 1024, 1024, 1024, 128, 512, 2);
  // Vt[b][d][kv] = (v @ Wv)^T  (B = v fp32, reg-staged; bv folded into PV)
  gemm8<0,1,0,0><<<dim3(256), 512, 0, stream>>>(Wvt, v, Vt, nullptr, 0.f,
      16, 0, 2048LL * 1024, 1024LL * 2048, 1024, 1024, 2048, 4, 32, 2);
  // S[b] = Qp[b] @ Kp[b]^T
  gemm8<0,0,0,0><<<dim3(256), 512, 0, stream>>>(Qp, Kp, S, nullptr, 0.f,
      16, 2048LL * 1024, 2048LL * 1024, 2048LL * 2048, 1024, 1024, 2048, 8, 64, 4);
  // P = softmax(S) in place
  softmax_rows<<<dim3(32768), 256, 0, stream>>>(S);
  // O[b] = P[b] @ Vt[b]^T + bv
  gemm8<0,0,1,0><<<dim3(256), 512, 0, stream>>>(S, Vt, O, bv, 1.f,
      32, 2048LL * 2048, 1024LL * 2048, 2048LL * 1024, 2048, 2048, 1024, 8, 32, 2);
  // out = O @ Wo + bo (fp32 out)
  gemm8<0,0,1,1><<<dim3(256), 512, 0, stream>>>(O, Wot, out, bo, 1.f,
      16, 0, 0, 0, 1024, 1024, 1024, 128, 512, 2);
}

// Round 9
// 967.497 us; speedup vs baseline: 1.1279x; 1.1279x over previous
//
#include <hip/hip_runtime.h>

typedef unsigned int u32;
typedef unsigned short u16;
typedef __attribute__((ext_vector_type(8))) __bf16 bf16x8;
typedef __attribute__((ext_vector_type(4))) float f32x4;

typedef __attribute__((address_space(1))) void as1_void;
typedef __attribute__((address_space(3))) void as3_void;

__device__ __forceinline__ u16 f2bf(float f){
  u32 u = __builtin_bit_cast(u32, f);
  return (u16)((u + 0x7FFFu + ((u >> 16) & 1u)) >> 16);
}
__device__ __forceinline__ float bf2f(u16 h){
  u32 u = ((u32)h) << 16;
  return __builtin_bit_cast(float, u);
}

__device__ __forceinline__ void gload16(const void* g, void* l){
  __builtin_amdgcn_global_load_lds((as1_void*)(unsigned long long)g, (as3_void*)l, 16, 0, 0);
}
__device__ __forceinline__ bf16x8 ldfrag(const char* p){
  return __builtin_bit_cast(bf16x8, *(const uint4*)p);
}
__device__ __forceinline__ uint4 cvt8(float4 a, float4 b){
  union { uint4 u; __bf16 h[8]; } uu;
  uu.h[0]=(__bf16)a.x; uu.h[1]=(__bf16)a.y; uu.h[2]=(__bf16)a.z; uu.h[3]=(__bf16)a.w;
  uu.h[4]=(__bf16)b.x; uu.h[5]=(__bf16)b.y; uu.h[6]=(__bf16)b.z; uu.h[7]=(__bf16)b.w;
  return uu.u;
}

// ---------- weight transpose-cast: out[n][k] = W[k][n] * scale (1024x1024) ----------
__global__ void wcast(const float* __restrict__ W, float scale, u16* __restrict__ out){
  __shared__ float t[32][33];
  int bx = blockIdx.x * 32, by = blockIdx.y * 32;
  int tx = threadIdx.x, ty = threadIdx.y;
  #pragma unroll
  for (int i = 0; i < 32; i += 8) t[ty + i][tx] = W[(size_t)(bx + ty + i) * 1024 + by + tx];
  __syncthreads();
  #pragma unroll
  for (int i = 0; i < 32; i += 8)
    out[(size_t)(by + ty + i) * 1024 + bx + tx] = f2bf(scale * t[tx][ty + i]);
}

// ---------- row softmax, in-place on bf16 S rows of length 2048 ----------
__global__ __launch_bounds__(256) void softmax_rows(u16* __restrict__ S){
  __shared__ float red[8];
  size_t row = blockIdx.x;
  uint4* p = (uint4*)(S + row * 2048);
  int tid = threadIdx.x;
  int lane = tid & 63, wave = tid >> 6;
  union { uint4 u4; u16 h[8]; } uu;
  uu.u4 = p[tid];
  float v[8];
  float m = -1e30f;
  #pragma unroll
  for (int j = 0; j < 8; j++){ v[j] = bf2f(uu.h[j]); m = fmaxf(m, v[j]); }
  #pragma unroll
  for (int o = 32; o; o >>= 1) m = fmaxf(m, __shfl_xor(m, o));
  if (lane == 0) red[wave] = m;
  __syncthreads();
  m = fmaxf(fmaxf(red[0], red[1]), fmaxf(red[2], red[3]));
  float s = 0.f;
  #pragma unroll
  for (int j = 0; j < 8; j++){ v[j] = __expf(v[j] - m); s += v[j]; }
  #pragma unroll
  for (int o = 32; o; o >>= 1) s += __shfl_xor(s, o);
  if (lane == 0) red[4 + wave] = s;
  __syncthreads();
  s = red[4] + red[5] + red[6] + red[7];
  float inv = 1.f / s;
  #pragma unroll
  for (int j = 0; j < 8; j++) uu.h[j] = f2bf(v[j] * inv);
  p[tid] = uu.u4;
}

// ---------- persistent 256x256 8-phase GEMM ----------
// C = A @ B^T (+col bias). Pure-bf16 path = R6 hoisted schedule (proven).
// AF32/BF32: fp32 operand reg-staged in 2 half-chunks (16 VGPR) with
// earliest-legal swizzled ds_writes; JIT frag reads; bias via epilogue loads.

template<int MO, int N0>
__device__ __forceinline__ void pm(f32x4 (&acc)[8][4], bf16x8 (&a)[4][2], bf16x8 (&b)[2][2]){
  __builtin_amdgcn_s_setprio(1);
  #pragma unroll
  for (int ks = 0; ks < 2; ks++)
    #pragma unroll
    for (int mm = 0; mm < 4; mm++)
      #pragma unroll
      for (int nn = 0; nn < 2; nn++)
        acc[MO + mm][N0 + nn] = __builtin_amdgcn_mfma_f32_16x16x32_bf16(
            a[mm][ks], b[nn][ks], acc[MO + mm][N0 + nn], 0, 0, 0);
  __builtin_amdgcn_s_setprio(0);
}

template<int AF32, int BF32, int BIAS, int OUTF32>
__global__ __launch_bounds__(512, 2) void gemm8(
    const void* __restrict__ A, const void* __restrict__ B, void* __restrict__ C,
    const float* __restrict__ bias, float bscale, int NT,
    long long sA, long long sB, long long sC,
    int lda, int ldb, int ldc, int gx, int gxy, int TPB)
{
  constexpr bool HOIST = (!AF32 && !BF32);
  __shared__ u16 sm[2][2][16384];   // [buf][A/B] 128 KiB
  char* smb = (char*)sm;

  int tid = threadIdx.x;
  int lane = tid & 63, wave = tid >> 6;
  int wr = wave >> 2, wc = wave & 3;
  int l15 = lane & 15, l4 = lane >> 4;

  int b = blockIdx.x;
  int lin0 = ((b & 7) * 32 + (b >> 3)) * TPB;   // XCD-chunked tile range

  // staging addressing: quarter i covers rows [i*64, i*64+64), 16B LDS chunk/lane
  int r = tid >> 3, cl = tid & 7;
  int ldsb = r * 128 + cl * 16;                    // linear dest (gload path)
  int ldsw = r * 128 + ((cl ^ (r & 7)) * 16);      // swizzled dest (ds_write path)
  u32 aoff[4], boff[4];
  #pragma unroll
  for (int i = 0; i < 4; i++){
    int row = i * 64 + r;
    if constexpr (AF32) aoff[i] = (u32)(((u32)row * (u32)lda + (u32)(cl * 8)) * 4u);
    else                aoff[i] = (u32)(((u32)row * (u32)lda + (u32)((cl ^ (r & 7)) * 8)) * 2u);
    if constexpr (BF32) boff[i] = (u32)(((u32)row * (u32)ldb + (u32)(cl * 8)) * 4u);
    else                boff[i] = (u32)(((u32)row * (u32)ldb + (u32)((cl ^ (r & 7)) * 8)) * 2u);
  }
  // fragment-read addressing (swizzled)
  u32 ardo[2], brdo[2];
  #pragma unroll
  for (int ks = 0; ks < 2; ks++){
    u32 sw = (u32)(((ks * 4 + l4) ^ (l15 & 7)) * 16);
    ardo[ks] = (u32)(wr * 16384 + l15 * 128) + sw;
    brdo[ks] = (u32)(wc * 8192 + l15 * 128) + sw;
  }

  auto tcoord = [&](int lin, int& x, int& y, int& z){
    z = lin / gxy; int rem = lin - z * gxy; y = rem / gx; x = rem - y * gx;
  };
  auto abase = [&](int lin){ int x, y, z; tcoord(lin, x, y, z);
    return (const char*)A + ((long long)z * sA + (long long)(x * 256) * lda) * (AF32 ? 4 : 2); };
  auto bbase = [&](int lin){ int x, y, z; tcoord(lin, x, y, z);
    return (const char*)B + ((long long)z * sB + (long long)(y * 256) * ldb) * (BF32 ? 4 : 2); };

  int tx, ty, tz;
  tcoord(lin0, tx, ty, tz);
  int row0 = tx * 256, col0 = ty * 256;
  long long zbC = tz;

  // bias preload for pure path only (mixed loads bias in epilogue)
  float bc0[4], bc1[4];
  if (HOIST && BIAS){
    int xx, yy, zz;
    tcoord(lin0, xx, yy, zz);
    int c0 = yy * 256 + wc * 64 + l15;
    #pragma unroll
    for (int n = 0; n < 4; n++) bc0[n] = bscale * bias[c0 + n * 16];
    tcoord(lin0 + (TPB > 1 ? 1 : 0), xx, yy, zz);
    c0 = yy * 256 + wc * 64 + l15;
    #pragma unroll
    for (int n = 0; n < 4; n++) bc1[n] = bscale * bias[c0 + n * 16];
  }

  // staging cursors: M -> tile of (s+1) [A_hi gload], P -> tile of (s+2)
  const char* AgM = abase(lin0);
  const char* AgP = AgM;
  const char* BgP = bbase(lin0);
  int km = 1, kp = 2, jm = 0, jp = 0, kk = 0, jj = 0;

#define STA(bse, i, kq, bb) gload16((bse) + aoff[i] + (size_t)(kq) * 128, smb + (bb) * 65536 + (i) * 8192 + ldsb)
#define STB(bse, i, kq, bb) gload16((bse) + boff[i] + (size_t)(kq) * 128, smb + (bb) * 65536 + 32768 + (i) * 8192 + ldsb)

  // ---- prologue: tiles 0 and 1 ----
  if constexpr (HOIST){
    // EXACT R6 order — vmcnt(6) relies on it (in-order completion).
    STA(AgM, 0, 0, 0); STA(AgM, 2, 0, 0);
    STB(BgP, 0, 0, 0); STB(BgP, 1, 0, 0); STB(BgP, 2, 0, 0); STB(BgP, 3, 0, 0);
    STA(AgM, 1, 0, 0); STA(AgM, 3, 0, 0);
    STA(AgM, 0, 1, 1); STA(AgM, 2, 1, 1);
    STB(BgP, 0, 1, 1); STB(BgP, 1, 1, 1); STB(BgP, 2, 1, 1); STB(BgP, 3, 1, 1);
    asm volatile("s_waitcnt vmcnt(6)" ::: "memory");
  } else {
    if constexpr (!AF32){   // BF32: A via gload; tile0 full + tile1 lo (hi comes at s=0 P0)
      STA(AgM, 0, 0, 0); STA(AgM, 2, 0, 0); STA(AgM, 1, 0, 0); STA(AgM, 3, 0, 0);
      STA(AgM, 0, 1, 1); STA(AgM, 2, 1, 1);
    }
    if constexpr (!BF32){   // AF32: B via gload; tiles 0,1 full
      STB(BgP, 0, 0, 0); STB(BgP, 1, 0, 0); STB(BgP, 2, 0, 0); STB(BgP, 3, 0, 0);
      STB(BgP, 0, 1, 1); STB(BgP, 1, 1, 1); STB(BgP, 2, 1, 1); STB(BgP, 3, 1, 1);
    }
    if constexpr (AF32){
      #pragma unroll
      for (int t = 0; t < 2; t++){
        float4 x0[4], x1[4];
        #pragma unroll
        for (int i = 0; i < 4; i++){
          const float4* p = (const float4*)(AgP + aoff[i] + (u32)t * 256u);
          x0[i] = p[0]; x1[i] = p[1];
        }
        #pragma unroll
        for (int i = 0; i < 4; i++)
          *(uint4*)(smb + t * 65536 + i * 8192 + ldsw) = cvt8(x0[i], x1[i]);
      }
    }
    if constexpr (BF32){
      #pragma unroll
      for (int t = 0; t < 2; t++){
        float4 x0[4], x1[4];
        #pragma unroll
        for (int i = 0; i < 4; i++){
          const float4* p = (const float4*)(BgP + boff[i] + (u32)t * 256u);
          x0[i] = p[0]; x1[i] = p[1];
        }
        #pragma unroll
        for (int i = 0; i < 4; i++)
          *(uint4*)(smb + t * 65536 + 32768 + i * 8192 + ldsw) = cvt8(x0[i], x1[i]);
      }
    }
    asm volatile("s_waitcnt vmcnt(0) lgkmcnt(0)" ::: "memory");
  }
  __builtin_amdgcn_s_barrier();

  f32x4 acc[8][4] = {};
  bf16x8 aLo[4][2], aHi[4][2], b01[2][2], b23[2][2];
  int S = TPB * NT;

  if constexpr (HOIST){
    // ======================= PURE-BF16 LOOP (R6, proven) =======================
    #pragma unroll
    for (int mm = 0; mm < 4; mm++)
      #pragma unroll
      for (int ks = 0; ks < 2; ks++)
        aLo[mm][ks] = ldfrag(smb + mm * 2048 + ardo[ks]);

    for (int s = 0; s < S; s++){
      int cur = s & 1;
      const char* Ab = smb + cur * 65536;
      const char* Bb = Ab + 32768;
      const char* AbN = smb + (cur ^ 1) * 65536;
      bool st1 = (s + 1 < S), st2 = (s + 2 < S);

      // ---- P0 ----
      if (st1){ STA(AgM, 1, km, cur ^ 1); STA(AgM, 3, km, cur ^ 1); }
      #pragma unroll
      for (int nn = 0; nn < 2; nn++)
        #pragma unroll
        for (int ks = 0; ks < 2; ks++)
          b01[nn][ks] = ldfrag(Bb + nn * 2048 + brdo[ks]);
      #pragma unroll
      for (int nn = 0; nn < 2; nn++)
        #pragma unroll
        for (int ks = 0; ks < 2; ks++)
          b23[nn][ks] = ldfrag(Bb + (2 + nn) * 2048 + brdo[ks]);
      __builtin_amdgcn_s_barrier();
      pm<0, 0>(acc, aLo, b01);
      __builtin_amdgcn_s_barrier();

      // ---- P1 ----
      if (st2){ STA(AgP, 0, kp, cur); STA(AgP, 2, kp, cur); }
      #pragma unroll
      for (int mm = 0; mm < 4; mm++)
        #pragma unroll
        for (int ks = 0; ks < 2; ks++)
          aHi[mm][ks] = ldfrag(Ab + (4 + mm) * 2048 + ardo[ks]);
      __builtin_amdgcn_s_barrier();
      pm<0, 2>(acc, aLo, b23);
      __builtin_amdgcn_s_barrier();

      // ---- P2 ----
      if (st2){ STB(BgP, 0, kp, cur); STB(BgP, 1, kp, cur); }
      __builtin_amdgcn_s_barrier();
      pm<4, 2>(acc, aHi, b23);
      __builtin_amdgcn_s_barrier();

      // ---- P3 ----
      if (st2){ STB(BgP, 2, kp, cur); STB(BgP, 3, kp, cur); }
      if (s < S - 2) asm volatile("s_waitcnt vmcnt(6)" ::: "memory");
      else           asm volatile("s_waitcnt vmcnt(0)" ::: "memory");
      __builtin_amdgcn_s_barrier();
      if (st1){
        #pragma unroll
        for (int mm = 0; mm < 4; mm++)
          #pragma unroll
          for (int ks = 0; ks < 2; ks++)
            aLo[mm][ks] = ldfrag(AbN + mm * 2048 + ardo[ks]);
      }
      pm<4, 0>(acc, aHi, b01);
      __builtin_amdgcn_s_barrier();

      // ---- cursors + epilogue ----
      if (++km == NT){ km = 0; if (++jm < TPB) AgM = abase(lin0 + jm); }
      if (++kp == NT){ kp = 0; if (++jp < TPB){ AgP = abase(lin0 + jp); BgP = bbase(lin0 + jp); } }
      if (++kk == NT){
        kk = 0;
        #pragma unroll
        for (int m = 0; m < 8; m++){
          #pragma unroll
          for (int n = 0; n < 4; n++){
            int gr0 = row0 + wr * 128 + m * 16 + l4 * 4;
            int gc  = col0 + wc * 64 + n * 16 + l15;
            float bcol = BIAS ? (jj == 0 ? bc0[n] : bc1[n]) : 0.f;
            #pragma unroll
            for (int j = 0; j < 4; j++){
              float vv = acc[m][n][j] + bcol;
              int gr = gr0 + j;
              if (OUTF32) ((float*)C)[zbC * sC + (size_t)gr * ldc + gc] = vv;
              else        ((u16*) C)[zbC * sC + (size_t)gr * ldc + gc] = f2bf(vv);
            }
            acc[m][n] = (f32x4){0.f, 0.f, 0.f, 0.f};
          }
        }
        if (++jj < TPB){
          tcoord(lin0 + jj, tx, ty, tz);
          row0 = tx * 256; col0 = ty * 256; zbC = tz;
        }
      }
    }
  } else {
    // ======================= MIXED (reg-staged fp32) LOOP =======================
    float4 svA[4], svB[4];   // half-chunk staging (16 VGPR each, short windows)

    for (int s = 0; s < S; s++){
      int cur = s & 1;
      const char* Ab = smb + cur * 65536;
      const char* Bb = Ab + 32768;
      char* AbW = smb + cur * 65536;        // s+2 targets (dbuf: s+2 == cur)
      char* BbW = AbW + 32768;
      bool st1 = (s + 1 < S), st2 = (s + 2 < S);

      // ---- P0: issue first fp32 half; gload staging; read aLo + b01 ----
      if constexpr (AF32){
        if (st2){
          const float4* p0 = (const float4*)(AgP + aoff[0] + (u32)kp * 256u);
          const float4* p2 = (const float4*)(AgP + aoff[2] + (u32)kp * 256u);
          svA[0] = p0[0]; svA[1] = p0[1]; svA[2] = p2[0]; svA[3] = p2[1];
        }
      } else {
        if (st1){ STA(AgM, 1, km, cur ^ 1); STA(AgM, 3, km, cur ^ 1); }
        if (st2){
          const float4* p0 = (const float4*)(BgP + boff[0] + (u32)kp * 256u);
          const float4* p1 = (const float4*)(BgP + boff[1] + (u32)kp * 256u);
          svA[0] = p0[0]; svA[1] = p0[1]; svA[2] = p1[0]; svA[3] = p1[1];
        }
      }
      #pragma unroll
      for (int mm = 0; mm < 4; mm++)
        #pragma unroll
        for (int ks = 0; ks < 2; ks++)
          aLo[mm][ks] = ldfrag(Ab + mm * 2048 + ardo[ks]);
      #pragma unroll
      for (int nn = 0; nn < 2; nn++)
        #pragma unroll
        for (int ks = 0; ks < 2; ks++)
          b01[nn][ks] = ldfrag(Bb + nn * 2048 + brdo[ks]);
      __builtin_amdgcn_s_barrier();
      pm<0, 0>(acc, aLo, b01);
      __builtin_amdgcn_s_barrier();

      // ---- P1: AF32: issue 2nd half + write 1st (aLo region free); read b23 ----
      if constexpr (AF32){
        if (st2){
          const float4* p1 = (const float4*)(AgP + aoff[1] + (u32)kp * 256u);
          const float4* p3 = (const float4*)(AgP + aoff[3] + (u32)kp * 256u);
          svB[0] = p1[0]; svB[1] = p1[1]; svB[2] = p3[0]; svB[3] = p3[1];
          *(uint4*)(AbW + 0 * 8192 + ldsw) = cvt8(svA[0], svA[1]);
          *(uint4*)(AbW + 2 * 8192 + ldsw) = cvt8(svA[2], svA[3]);
        }
      } else {
        if (st2){ STA(AgP, 0, kp, cur); STA(AgP, 2, kp, cur); }
      }
      #pragma unroll
      for (int nn = 0; nn < 2; nn++)
        #pragma unroll
        for (int ks = 0; ks < 2; ks++)
          b23[nn][ks] = ldfrag(Bb + (2 + nn) * 2048 + brdo[ks]);
      __builtin_amdgcn_s_barrier();
      pm<0, 2>(acc, aLo, b23);
      __builtin_amdgcn_s_barrier();

      // ---- P2: AF32: STB half; BF32: issue 2nd B half + write 1st; read aHi ----
      if constexpr (AF32){
        if (st2){ STB(BgP, 0, kp, cur); STB(BgP, 1, kp, cur); }
      } else {
        if (st2){
          const float4* p2 = (const float4*)(BgP + boff[2] + (u32)kp * 256u);
          const float4* p3 = (const float4*)(BgP + boff[3] + (u32)kp * 256u);
          svB[0] = p2[0]; svB[1] = p2[1]; svB[2] = p3[0]; svB[3] = p3[1];
          *(uint4*)(BbW + 0 * 8192 + ldsw) = cvt8(svA[0], svA[1]);
          *(uint4*)(BbW + 1 * 8192 + ldsw) = cvt8(svA[2], svA[3]);
        }
      }
      #pragma unroll
      for (int mm = 0; mm < 4; mm++)
        #pragma unroll
        for (int ks = 0; ks < 2; ks++)
          aHi[mm][ks] = ldfrag(Ab + (4 + mm) * 2048 + ardo[ks]);
      __builtin_amdgcn_s_barrier();
      pm<4, 2>(acc, aHi, b23);
      __builtin_amdgcn_s_barrier();

      // ---- P3: finish staging; counted vmcnt + lgkm drain; MFMA on held b01 ----
      if constexpr (AF32){
        if (st2){
          STB(BgP, 2, kp, cur); STB(BgP, 3, kp, cur);
          *(uint4*)(AbW + 1 * 8192 + ldsw) = cvt8(svB[0], svB[1]);
          *(uint4*)(AbW + 3 * 8192 + ldsw) = cvt8(svB[2], svB[3]);
        }
      } else {
        if (st2){
          *(uint4*)(BbW + 2 * 8192 + ldsw) = cvt8(svB[0], svB[1]);
          *(uint4*)(BbW + 3 * 8192 + ldsw) = cvt8(svB[2], svB[3]);
        }
      }
      if (AF32 && s < S - 2) asm volatile("s_waitcnt vmcnt(4) lgkmcnt(0)" ::: "memory");
      else                   asm volatile("s_waitcnt vmcnt(0) lgkmcnt(0)" ::: "memory");
      __builtin_amdgcn_s_barrier();
      pm<4, 0>(acc, aHi, b01);
      __builtin_amdgcn_s_barrier();

      // ---- cursors + epilogue ----
      if constexpr (!AF32){
        if (++km == NT){ km = 0; if (++jm < TPB) AgM = abase(lin0 + jm); }
      }
      if (++kp == NT){ kp = 0; if (++jp < TPB){ AgP = abase(lin0 + jp); BgP = bbase(lin0 + jp); } }
      if (++kk == NT){
        kk = 0;
        float bb[4];
        if (BIAS){
          #pragma unroll
          for (int n = 0; n < 4; n++)
            bb[n] = bscale * bias[col0 + wc * 64 + n * 16 + l15];
        }
        #pragma unroll
        for (int m = 0; m < 8; m++){
          #pragma unroll
          for (int n = 0; n < 4; n++){
            int gr0 = row0 + wr * 128 + m * 16 + l4 * 4;
            int gc  = col0 + wc * 64 + n * 16 + l15;
            float bcol = BIAS ? bb[n] : 0.f;
            #pragma unroll
            for (int j = 0; j < 4; j++){
              float vv = acc[m][n][j] + bcol;
              int gr = gr0 + j;
              if (OUTF32) ((float*)C)[zbC * sC + (size_t)gr * ldc + gc] = vv;
              else        ((u16*) C)[zbC * sC + (size_t)gr * ldc + gc] = f2bf(vv);
            }
            acc[m][n] = (f32x4){0.f, 0.f, 0.f, 0.f};
          }
        }
        if (++jj < TPB){
          tcoord(lin0 + jj, tx, ty, tz);
          row0 = tx * 256; col0 = ty * 256; zbC = tz;
        }
      }
    }
  }
#undef STA
#undef STB
}

extern "C" void kernel_launch(void* const* d_in, const int* in_sizes, int n_in,
                              void* d_out, int out_size, void* d_ws, size_t ws_size,
                              hipStream_t stream){
  const float* q  = (const float*)d_in[0];
  const float* k  = (const float*)d_in[1];
  const float* v  = (const float*)d_in[2];
  const float* Wq = (const float*)d_in[3];
  const float* bq = (const float*)d_in[4];
  const float* Wk = (const float*)d_in[5];
  const float* bk = (const float*)d_in[6];
  const float* Wv = (const float*)d_in[7];
  const float* bv = (const float*)d_in[8];
  const float* Wo = (const float*)d_in[9];
  const float* bo = (const float*)d_in[10];

  char* ws = (char*)d_ws;
  const size_t MB = (size_t)1 << 20;
  u16* Wqt = (u16*)(ws + 0 * MB);
  u16* Wkt = (u16*)(ws + 2 * MB);
  u16* Wvt = (u16*)(ws + 4 * MB);
  u16* Wot = (u16*)(ws + 6 * MB);
  u16* Qp  = (u16*)(ws + 8 * MB);    // [32768][1024] bf16
  u16* Kp  = (u16*)(ws + 72 * MB);   // [32768][1024] bf16
  u16* Vt  = (u16*)(ws + 136 * MB);  // [16][1024][2048] bf16
  u16* S   = (u16*)(ws + 200 * MB);  // [16][2048][2048] bf16 (P in-place)
  u16* O   = (u16*)(ws + 328 * MB);  // [32768][1024] bf16
  float* out = (float*)d_out;

  dim3 wb(32, 8);
  wcast<<<dim3(32, 32), wb, 0, stream>>>(Wq, 1.f / 32.f, Wqt);  // fold 1/sqrt(D)
  wcast<<<dim3(32, 32), wb, 0, stream>>>(Wk, 1.f, Wkt);
  wcast<<<dim3(32, 32), wb, 0, stream>>>(Wv, 1.f, Wvt);
  wcast<<<dim3(32, 32), wb, 0, stream>>>(Wo, 1.f, Wot);

  // Q' = (q @ Wq + bq)/32   (A = q fp32, reg-staged)
  gemm8<1,0,1,0><<<dim3(256), 512, 0, stream>>>(q, Wqt, Qp, bq, 1.f/32.f,
      16, 0, 0, 0, 1024, 1024, 1024, 128, 512, 2);
  // K' = k @ Wk + bk
  gemm8<1,0,1,0><<<dim3(256), 512, 0, stream>>>(k, Wkt, Kp, bk, 1.f,
      16, 0, 0, 0, 1024, 1024, 1024, 128, 512, 2);
  // Vt[b][d][kv] = (v @ Wv)^T  (B = v fp32, reg-staged; bv folded into PV)
  gemm8<0,1,0,0><<<dim3(256), 512, 0, stream>>>(Wvt, v, Vt, nullptr, 0.f,
      16, 0, 2048LL * 1024, 1024LL * 2048, 1024, 1024, 2048, 4, 32, 2);
  // S[b] = Qp[b] @ Kp[b]^T
  gemm8<0,0,0,0><<<dim3(256), 512, 0, stream>>>(Qp, Kp, S, nullptr, 0.f,
      16, 2048LL * 1024, 2048LL * 1024, 2048LL * 2048, 1024, 1024, 2048, 8, 64, 4);
  // P = softmax(S) in place
  softmax_rows<<<dim3(32768), 256, 0, stream>>>(S);
  // O[b] = P[b] @ Vt[b]^T + bv
  gemm8<0,0,1,0><<<dim3(256), 512, 0, stream>>>(S, Vt, O, bv, 1.f,
      32, 2048LL * 2048, 1024LL * 2048, 2048LL * 1024, 2048, 2048, 1024, 8, 32, 2);
  // out = O @ Wo + bo (fp32 out)
  gemm8<0,0,1,1><<<dim3(256), 512, 0, stream>>>(O, Wot, out, bo, 1.f,
      16, 0, 0, 0, 1024, 1024, 1024, 128, 512, 2);
}

// Round 10
// 744.099 us; speedup vs baseline: 1.4665x; 1.3002x over previous
//
#include <hip/hip_runtime.h>

typedef unsigned int u32;
typedef unsigned short u16;
typedef __attribute__((ext_vector_type(8))) __bf16 bf16x8;
typedef __attribute__((ext_vector_type(4))) float f32x4;

typedef __attribute__((address_space(1))) void as1_void;
typedef __attribute__((address_space(3))) void as3_void;

__device__ __forceinline__ u16 f2bf(float f){
  u32 u = __builtin_bit_cast(u32, f);
  return (u16)((u + 0x7FFFu + ((u >> 16) & 1u)) >> 16);
}
__device__ __forceinline__ float bf2f(u16 h){
  u32 u = ((u32)h) << 16;
  return __builtin_bit_cast(float, u);
}

__device__ __forceinline__ void gload16(const void* g, void* l){
  __builtin_amdgcn_global_load_lds((as1_void*)(unsigned long long)g, (as3_void*)l, 16, 0, 0);
}
__device__ __forceinline__ bf16x8 ldfrag(const char* p){
  return __builtin_bit_cast(bf16x8, *(const uint4*)p);
}

// ---------- weight transpose-cast: out[n][k] = W[k][n] * scale (1024x1024) ----------
__global__ void wcast(const float* __restrict__ W, float scale, u16* __restrict__ out){
  __shared__ float t[32][33];
  int bx = blockIdx.x * 32, by = blockIdx.y * 32;
  int tx = threadIdx.x, ty = threadIdx.y;
  #pragma unroll
  for (int i = 0; i < 32; i += 8) t[ty + i][tx] = W[(size_t)(bx + ty + i) * 1024 + by + tx];
  __syncthreads();
  #pragma unroll
  for (int i = 0; i < 32; i += 8)
    out[(size_t)(by + ty + i) * 1024 + bx + tx] = f2bf(scale * t[tx][ty + i]);
}

// ---------- fp32 -> bf16 cast, 8 elems/thread ----------
__global__ __launch_bounds__(256) void castbf(const float* __restrict__ in, u16* __restrict__ out, int n8){
  int stride = gridDim.x * blockDim.x;
  for (int i = blockIdx.x * blockDim.x + threadIdx.x; i < n8; i += stride){
    const float4* p = (const float4*)(in + (size_t)i * 8);
    float4 f0 = p[0], f1 = p[1];
    union { uint4 u; u16 h[8]; } uu;
    uu.h[0]=f2bf(f0.x); uu.h[1]=f2bf(f0.y); uu.h[2]=f2bf(f0.z); uu.h[3]=f2bf(f0.w);
    uu.h[4]=f2bf(f1.x); uu.h[5]=f2bf(f1.y); uu.h[6]=f2bf(f1.z); uu.h[7]=f2bf(f1.w);
    ((uint4*)out)[i] = uu.u;
  }
}

// ---------- row softmax, in-place on bf16 S rows of length 2048 ----------
__global__ __launch_bounds__(256) void softmax_rows(u16* __restrict__ S){
  __shared__ float red[8];
  size_t row = blockIdx.x;
  uint4* p = (uint4*)(S + row * 2048);
  int tid = threadIdx.x;
  int lane = tid & 63, wave = tid >> 6;
  union { uint4 u4; u16 h[8]; } uu;
  uu.u4 = p[tid];
  float v[8];
  float m = -1e30f;
  #pragma unroll
  for (int j = 0; j < 8; j++){ v[j] = bf2f(uu.h[j]); m = fmaxf(m, v[j]); }
  #pragma unroll
  for (int o = 32; o; o >>= 1) m = fmaxf(m, __shfl_xor(m, o));
  if (lane == 0) red[wave] = m;
  __syncthreads();
  m = fmaxf(fmaxf(red[0], red[1]), fmaxf(red[2], red[3]));
  float s = 0.f;
  #pragma unroll
  for (int j = 0; j < 8; j++){ v[j] = __expf(v[j] - m); s += v[j]; }
  #pragma unroll
  for (int o = 32; o; o >>= 1) s += __shfl_xor(s, o);
  if (lane == 0) red[4 + wave] = s;
  __syncthreads();
  s = red[4] + red[5] + red[6] + red[7];
  float inv = 1.f / s;
  #pragma unroll
  for (int j = 0; j < 8; j++) uu.h[j] = f2bf(v[j] * inv);
  p[tid] = uu.u4;
}

template<int MO, int N0>
__device__ __forceinline__ void pm(f32x4 (&acc)[8][4], bf16x8 (&a)[4][2], bf16x8 (&b)[2][2]){
  __builtin_amdgcn_s_setprio(1);
  #pragma unroll
  for (int ks = 0; ks < 2; ks++)
    #pragma unroll
    for (int mm = 0; mm < 4; mm++)
      #pragma unroll
      for (int nn = 0; nn < 2; nn++)
        acc[MO + mm][N0 + nn] = __builtin_amdgcn_mfma_f32_16x16x32_bf16(
            a[mm][ks], b[nn][ks], acc[MO + mm][N0 + nn], 0, 0, 0);
  __builtin_amdgcn_s_setprio(0);
}

// ---------- persistent 256x256 8-phase GEMM (R6, proven) ----------
template<int BIAS, int OUTF32>
__global__ __launch_bounds__(512, 2) void gemm8(
    const u16* __restrict__ A, const u16* __restrict__ B, void* __restrict__ C,
    const float* __restrict__ bias, float bscale, int NT,
    long long sA, long long sB, long long sC,
    int lda, int ldb, int ldc, int gx, int gxy, int TPB)
{
  __shared__ u16 sm[2][2][16384];   // [buf][A/B] 128 KiB
  char* smb = (char*)sm;

  int tid = threadIdx.x;
  int lane = tid & 63, wave = tid >> 6;
  int wr = wave >> 2, wc = wave & 3;
  int l15 = lane & 15, l4 = lane >> 4;

  int b = blockIdx.x;
  int lin0 = ((b & 7) * 32 + (b >> 3)) * TPB;

  int r = tid >> 3, cl = tid & 7;
  int ldsb = r * 128 + cl * 16;
  u32 aoff[4], boff[4];
  #pragma unroll
  for (int i = 0; i < 4; i++){
    int row = i * 64 + r;
    int ksw = (cl ^ (r & 7)) * 8;
    aoff[i] = (u32)(((u32)row * (u32)lda + (u32)ksw) * 2u);
    boff[i] = (u32)(((u32)row * (u32)ldb + (u32)ksw) * 2u);
  }
  u32 ardo[2], brdo[2];
  #pragma unroll
  for (int ks = 0; ks < 2; ks++){
    u32 sw = (u32)(((ks * 4 + l4) ^ (l15 & 7)) * 16);
    ardo[ks] = (u32)(wr * 16384 + l15 * 128) + sw;
    brdo[ks] = (u32)(wc * 8192 + l15 * 128) + sw;
  }

  auto tcoord = [&](int lin, int& x, int& y, int& z){
    z = lin / gxy; int rem = lin - z * gxy; y = rem / gx; x = rem - y * gx;
  };
  auto abase = [&](int lin){ int x, y, z; tcoord(lin, x, y, z);
    return (const char*)(A + (long long)z * sA + (size_t)(x * 256) * lda); };
  auto bbase = [&](int lin){ int x, y, z; tcoord(lin, x, y, z);
    return (const char*)(B + (long long)z * sB + (size_t)(y * 256) * ldb); };

  int tx, ty, tz;
  tcoord(lin0, tx, ty, tz);
  int row0 = tx * 256, col0 = ty * 256;
  long long zbC = tz;

  float bc0[4], bc1[4];
  if (BIAS){
    int xx, yy, zz;
    tcoord(lin0, xx, yy, zz);
    int c0 = yy * 256 + wc * 64 + l15;
    #pragma unroll
    for (int n = 0; n < 4; n++) bc0[n] = bscale * bias[c0 + n * 16];
    tcoord(lin0 + (TPB > 1 ? 1 : 0), xx, yy, zz);
    c0 = yy * 256 + wc * 64 + l15;
    #pragma unroll
    for (int n = 0; n < 4; n++) bc1[n] = bscale * bias[c0 + n * 16];
  }

  const char* AgM = abase(lin0);
  const char* AgP = AgM;
  const char* BgP = bbase(lin0);
  int km = 1, kp = 2, jm = 0, jp = 0, kk = 0, jj = 0;

#define STA(bse, i, kq, bb) gload16((bse) + aoff[i] + (size_t)(kq) * 128, smb + (bb) * 65536 + (i) * 8192 + ldsb)
#define STB(bse, i, kq, bb) gload16((bse) + boff[i] + (size_t)(kq) * 128, smb + (bb) * 65536 + 32768 + (i) * 8192 + ldsb)

  // prologue — EXACT R6 order (vmcnt(6) is positional)
  STA(AgM, 0, 0, 0); STA(AgM, 2, 0, 0);
  STB(BgP, 0, 0, 0); STB(BgP, 1, 0, 0); STB(BgP, 2, 0, 0); STB(BgP, 3, 0, 0);
  STA(AgM, 1, 0, 0); STA(AgM, 3, 0, 0);
  STA(AgM, 0, 1, 1); STA(AgM, 2, 1, 1);
  STB(BgP, 0, 1, 1); STB(BgP, 1, 1, 1); STB(BgP, 2, 1, 1); STB(BgP, 3, 1, 1);
  asm volatile("s_waitcnt vmcnt(6)" ::: "memory");
  __builtin_amdgcn_s_barrier();

  f32x4 acc[8][4] = {};
  bf16x8 aLo[4][2], aHi[4][2], b01[2][2], b23[2][2];
  int S = TPB * NT;

  #pragma unroll
  for (int mm = 0; mm < 4; mm++)
    #pragma unroll
    for (int ks = 0; ks < 2; ks++)
      aLo[mm][ks] = ldfrag(smb + mm * 2048 + ardo[ks]);

  for (int s = 0; s < S; s++){
    int cur = s & 1;
    const char* Ab = smb + cur * 65536;
    const char* Bb = Ab + 32768;
    const char* AbN = smb + (cur ^ 1) * 65536;
    bool st1 = (s + 1 < S), st2 = (s + 2 < S);

    // ---- P0 ----
    if (st1){ STA(AgM, 1, km, cur ^ 1); STA(AgM, 3, km, cur ^ 1); }
    #pragma unroll
    for (int nn = 0; nn < 2; nn++)
      #pragma unroll
      for (int ks = 0; ks < 2; ks++)
        b01[nn][ks] = ldfrag(Bb + nn * 2048 + brdo[ks]);
    #pragma unroll
    for (int nn = 0; nn < 2; nn++)
      #pragma unroll
      for (int ks = 0; ks < 2; ks++)
        b23[nn][ks] = ldfrag(Bb + (2 + nn) * 2048 + brdo[ks]);
    __builtin_amdgcn_s_barrier();
    pm<0, 0>(acc, aLo, b01);
    __builtin_amdgcn_s_barrier();

    // ---- P1 ----
    if (st2){ STA(AgP, 0, kp, cur); STA(AgP, 2, kp, cur); }
    #pragma unroll
    for (int mm = 0; mm < 4; mm++)
      #pragma unroll
      for (int ks = 0; ks < 2; ks++)
        aHi[mm][ks] = ldfrag(Ab + (4 + mm) * 2048 + ardo[ks]);
    __builtin_amdgcn_s_barrier();
    pm<0, 2>(acc, aLo, b23);
    __builtin_amdgcn_s_barrier();

    // ---- P2 ----
    if (st2){ STB(BgP, 0, kp, cur); STB(BgP, 1, kp, cur); }
    __builtin_amdgcn_s_barrier();
    pm<4, 2>(acc, aHi, b23);
    __builtin_amdgcn_s_barrier();

    // ---- P3 ----
    if (st2){ STB(BgP, 2, kp, cur); STB(BgP, 3, kp, cur); }
    if (s < S - 2) asm volatile("s_waitcnt vmcnt(6)" ::: "memory");
    else           asm volatile("s_waitcnt vmcnt(0)" ::: "memory");
    __builtin_amdgcn_s_barrier();
    if (st1){
      #pragma unroll
      for (int mm = 0; mm < 4; mm++)
        #pragma unroll
        for (int ks = 0; ks < 2; ks++)
          aLo[mm][ks] = ldfrag(AbN + mm * 2048 + ardo[ks]);
    }
    pm<4, 0>(acc, aHi, b01);
    __builtin_amdgcn_s_barrier();

    // ---- cursors + epilogue ----
    if (++km == NT){ km = 0; if (++jm < TPB) AgM = abase(lin0 + jm); }
    if (++kp == NT){ kp = 0; if (++jp < TPB){ AgP = abase(lin0 + jp); BgP = bbase(lin0 + jp); } }
    if (++kk == NT){
      kk = 0;
      #pragma unroll
      for (int m = 0; m < 8; m++){
        #pragma unroll
        for (int n = 0; n < 4; n++){
          int gr0 = row0 + wr * 128 + m * 16 + l4 * 4;
          int gc  = col0 + wc * 64 + n * 16 + l15;
          float bcol = BIAS ? (jj == 0 ? bc0[n] : bc1[n]) : 0.f;
          #pragma unroll
          for (int j = 0; j < 4; j++){
            float vv = acc[m][n][j] + bcol;
            int gr = gr0 + j;
            if (OUTF32) ((float*)C)[zbC * sC + (size_t)gr * ldc + gc] = vv;
            else        ((u16*) C)[zbC * sC + (size_t)gr * ldc + gc] = f2bf(vv);
          }
          acc[m][n] = (f32x4){0.f, 0.f, 0.f, 0.f};
        }
      }
      if (++jj < TPB){
        tcoord(lin0 + jj, tx, ty, tz);
        row0 = tx * 256; col0 = ty * 256; zbC = tz;
      }
    }
  }
#undef STA
#undef STB
}

// ---------- EXPERIMENT: merged 2-phase variant (4 barriers/step) ----------
template<int BIAS, int OUTF32>
__global__ __launch_bounds__(512, 2) void gemm4(
    const u16* __restrict__ A, const u16* __restrict__ B, void* __restrict__ C,
    const float* __restrict__ bias, float bscale, int NT,
    long long sA, long long sB, long long sC,
    int lda, int ldb, int ldc, int gx, int gxy, int TPB)
{
  __shared__ u16 sm[2][2][16384];
  char* smb = (char*)sm;

  int tid = threadIdx.x;
  int lane = tid & 63, wave = tid >> 6;
  int wr = wave >> 2, wc = wave & 3;
  int l15 = lane & 15, l4 = lane >> 4;

  int b = blockIdx.x;
  int lin0 = ((b & 7) * 32 + (b >> 3)) * TPB;

  int r = tid >> 3, cl = tid & 7;
  int ldsb = r * 128 + cl * 16;
  u32 aoff[4], boff[4];
  #pragma unroll
  for (int i = 0; i < 4; i++){
    int row = i * 64 + r;
    int ksw = (cl ^ (r & 7)) * 8;
    aoff[i] = (u32)(((u32)row * (u32)lda + (u32)ksw) * 2u);
    boff[i] = (u32)(((u32)row * (u32)ldb + (u32)ksw) * 2u);
  }
  u32 ardo[2], brdo[2];
  #pragma unroll
  for (int ks = 0; ks < 2; ks++){
    u32 sw = (u32)(((ks * 4 + l4) ^ (l15 & 7)) * 16);
    ardo[ks] = (u32)(wr * 16384 + l15 * 128) + sw;
    brdo[ks] = (u32)(wc * 8192 + l15 * 128) + sw;
  }

  auto tcoord = [&](int lin, int& x, int& y, int& z){
    z = lin / gxy; int rem = lin - z * gxy; y = rem / gx; x = rem - y * gx;
  };
  auto abase = [&](int lin){ int x, y, z; tcoord(lin, x, y, z);
    return (const char*)(A + (long long)z * sA + (size_t)(x * 256) * lda); };
  auto bbase = [&](int lin){ int x, y, z; tcoord(lin, x, y, z);
    return (const char*)(B + (long long)z * sB + (size_t)(y * 256) * ldb); };

  int tx, ty, tz;
  tcoord(lin0, tx, ty, tz);
  int row0 = tx * 256, col0 = ty * 256;
  long long zbC = tz;

  float bc0[4], bc1[4];
  if (BIAS){
    int xx, yy, zz;
    tcoord(lin0, xx, yy, zz);
    int c0 = yy * 256 + wc * 64 + l15;
    #pragma unroll
    for (int n = 0; n < 4; n++) bc0[n] = bscale * bias[c0 + n * 16];
    tcoord(lin0 + (TPB > 1 ? 1 : 0), xx, yy, zz);
    c0 = yy * 256 + wc * 64 + l15;
    #pragma unroll
    for (int n = 0; n < 4; n++) bc1[n] = bscale * bias[c0 + n * 16];
  }

  const char* AgM = abase(lin0);
  const char* AgP = AgM;
  const char* BgP = bbase(lin0);
  int km = 1, kp = 2, jm = 0, jp = 0, kk = 0, jj = 0;

#define STA(bse, i, kq, bb) gload16((bse) + aoff[i] + (size_t)(kq) * 128, smb + (bb) * 65536 + (i) * 8192 + ldsb)
#define STB(bse, i, kq, bb) gload16((bse) + boff[i] + (size_t)(kq) * 128, smb + (bb) * 65536 + 32768 + (i) * 8192 + ldsb)

  // prologue: tile0 full (8), then ALo(1) (2), then B(1) (4). vmcnt(6) -> tile0 done.
  STA(AgM, 0, 0, 0); STA(AgM, 1, 0, 0); STA(AgM, 2, 0, 0); STA(AgM, 3, 0, 0);
  STB(BgP, 0, 0, 0); STB(BgP, 1, 0, 0); STB(BgP, 2, 0, 0); STB(BgP, 3, 0, 0);
  STA(AgM, 0, 1, 1); STA(AgM, 2, 1, 1);
  STB(BgP, 0, 1, 1); STB(BgP, 1, 1, 1); STB(BgP, 2, 1, 1); STB(BgP, 3, 1, 1);
  asm volatile("s_waitcnt vmcnt(6)" ::: "memory");
  __builtin_amdgcn_s_barrier();

  f32x4 acc[8][4] = {};
  bf16x8 aLo[4][2], aHi[4][2], b01[2][2], b23[2][2];
  int S = TPB * NT;

  #pragma unroll
  for (int mm = 0; mm < 4; mm++)
    #pragma unroll
    for (int ks = 0; ks < 2; ks++)
      aLo[mm][ks] = ldfrag(smb + mm * 2048 + ardo[ks]);

  for (int s = 0; s < S; s++){
    int cur = s & 1;
    const char* Ab = smb + cur * 65536;
    const char* Bb = Ab + 32768;
    const char* AbN = smb + (cur ^ 1) * 65536;
    bool st1 = (s + 1 < S), st2 = (s + 2 < S);

    // ---- Ph0: stage A_hi(s+1) -> other buf, A_lo(s+2) -> this buf; read all B ----
    if (st1){ STA(AgM, 1, km, cur ^ 1); STA(AgM, 3, km, cur ^ 1); }
    if (st2){ STA(AgP, 0, kp, cur);  STA(AgP, 2, kp, cur); }
    #pragma unroll
    for (int nn = 0; nn < 2; nn++)
      #pragma unroll
      for (int ks = 0; ks < 2; ks++)
        b01[nn][ks] = ldfrag(Bb + nn * 2048 + brdo[ks]);
    #pragma unroll
    for (int nn = 0; nn < 2; nn++)
      #pragma unroll
      for (int ks = 0; ks < 2; ks++)
        b23[nn][ks] = ldfrag(Bb + (2 + nn) * 2048 + brdo[ks]);
    __builtin_amdgcn_s_barrier();
    pm<0, 0>(acc, aLo, b01);
    pm<0, 2>(acc, aLo, b23);
    __builtin_amdgcn_s_barrier();

    // ---- Ph1: stage B(s+2) -> this buf; read aHi; counted vmcnt; hoist aLo(s+1) ----
    if (st2){ STB(BgP, 0, kp, cur); STB(BgP, 1, kp, cur); STB(BgP, 2, kp, cur); STB(BgP, 3, kp, cur); }
    #pragma unroll
    for (int mm = 0; mm < 4; mm++)
      #pragma unroll
      for (int ks = 0; ks < 2; ks++)
        aHi[mm][ks] = ldfrag(Ab + (4 + mm) * 2048 + ardo[ks]);
    if (s < S - 2) asm volatile("s_waitcnt vmcnt(6)" ::: "memory");
    else           asm volatile("s_waitcnt vmcnt(0)" ::: "memory");
    __builtin_amdgcn_s_barrier();
    if (st1){
      #pragma unroll
      for (int mm = 0; mm < 4; mm++)
        #pragma unroll
        for (int ks = 0; ks < 2; ks++)
          aLo[mm][ks] = ldfrag(AbN + mm * 2048 + ardo[ks]);
    }
    pm<4, 0>(acc, aHi, b01);
    pm<4, 2>(acc, aHi, b23);
    __builtin_amdgcn_s_barrier();

    // ---- cursors + epilogue ----
    if (++km == NT){ km = 0; if (++jm < TPB) AgM = abase(lin0 + jm); }
    if (++kp == NT){ kp = 0; if (++jp < TPB){ AgP = abase(lin0 + jp); BgP = bbase(lin0 + jp); } }
    if (++kk == NT){
      kk = 0;
      #pragma unroll
      for (int m = 0; m < 8; m++){
        #pragma unroll
        for (int n = 0; n < 4; n++){
          int gr0 = row0 + wr * 128 + m * 16 + l4 * 4;
          int gc  = col0 + wc * 64 + n * 16 + l15;
          float bcol = BIAS ? (jj == 0 ? bc0[n] : bc1[n]) : 0.f;
          #pragma unroll
          for (int j = 0; j < 4; j++){
            float vv = acc[m][n][j] + bcol;
            int gr = gr0 + j;
            if (OUTF32) ((float*)C)[zbC * sC + (size_t)gr * ldc + gc] = vv;
            else        ((u16*) C)[zbC * sC + (size_t)gr * ldc + gc] = f2bf(vv);
          }
          acc[m][n] = (f32x4){0.f, 0.f, 0.f, 0.f};
        }
      }
      if (++jj < TPB){
        tcoord(lin0 + jj, tx, ty, tz);
        row0 = tx * 256; col0 = ty * 256; zbC = tz;
      }
    }
  }
#undef STA
#undef STB
}

extern "C" void kernel_launch(void* const* d_in, const int* in_sizes, int n_in,
                              void* d_out, int out_size, void* d_ws, size_t ws_size,
                              hipStream_t stream){
  const float* q  = (const float*)d_in[0];
  const float* k  = (const float*)d_in[1];
  const float* v  = (const float*)d_in[2];
  const float* Wq = (const float*)d_in[3];
  const float* bq = (const float*)d_in[4];
  const float* Wk = (const float*)d_in[5];
  const float* bk = (const float*)d_in[6];
  const float* Wv = (const float*)d_in[7];
  const float* bv = (const float*)d_in[8];
  const float* Wo = (const float*)d_in[9];
  const float* bo = (const float*)d_in[10];

  char* ws = (char*)d_ws;
  const size_t MB = (size_t)1 << 20;
  u16* Wqt = (u16*)(ws + 0 * MB);
  u16* Wkt = (u16*)(ws + 2 * MB);
  u16* Wvt = (u16*)(ws + 4 * MB);
  u16* Wot = (u16*)(ws + 6 * MB);
  u16* Qp  = (u16*)(ws + 8 * MB);    // [32768][1024] bf16
  u16* Kp  = (u16*)(ws + 72 * MB);   // [32768][1024] bf16
  u16* Vt  = (u16*)(ws + 136 * MB);  // [16][1024][2048] bf16
  u16* S   = (u16*)(ws + 200 * MB);  // [16][2048][2048] bf16 (P in-place)
  u16* O   = (u16*)(ws + 328 * MB);  // [32768][1024] bf16
  u16* X   = (u16*)(ws + 200 * MB);  // bf16 staging for q/k/v (dead before S written)
  float* out = (float*)d_out;

  dim3 wb(32, 8);
  wcast<<<dim3(32, 32), wb, 0, stream>>>(Wq, 1.f / 32.f, Wqt);  // fold 1/sqrt(D)
  wcast<<<dim3(32, 32), wb, 0, stream>>>(Wk, 1.f, Wkt);
  wcast<<<dim3(32, 32), wb, 0, stream>>>(Wv, 1.f, Wvt);
  wcast<<<dim3(32, 32), wb, 0, stream>>>(Wo, 1.f, Wot);

  const int n8 = 16 * 2048 * 1024 / 8;

  // Q' = (q @ Wq + bq)/32
  castbf<<<dim3(2048), 256, 0, stream>>>(q, X, n8);
  gemm8<1,0><<<dim3(256), 512, 0, stream>>>(X, Wqt, Qp, bq, 1.f/32.f,
      16, 0, 0, 0, 1024, 1024, 1024, 128, 512, 2);
  // K' = k @ Wk + bk
  castbf<<<dim3(2048), 256, 0, stream>>>(k, X, n8);
  gemm8<1,0><<<dim3(256), 512, 0, stream>>>(X, Wkt, Kp, bk, 1.f,
      16, 0, 0, 0, 1024, 1024, 1024, 128, 512, 2);
  // Vt[b][d][kv] = (v @ Wv)^T  (bv folded into PV epilogue)
  castbf<<<dim3(2048), 256, 0, stream>>>(v, X, n8);
  gemm8<0,0><<<dim3(256), 512, 0, stream>>>(Wvt, X, Vt, nullptr, 0.f,
      16, 0, 2048LL * 1024, 1024LL * 2048, 1024, 1024, 2048, 4, 32, 2);
  // S[b] = Qp[b] @ Kp[b]^T   -- EXPERIMENT: merged 2-phase gemm4
  gemm4<0,0><<<dim3(256), 512, 0, stream>>>(Qp, Kp, S, nullptr, 0.f,
      16, 2048LL * 1024, 2048LL * 1024, 2048LL * 2048, 1024, 1024, 2048, 8, 64, 4);
  // P = softmax(S) in place
  softmax_rows<<<dim3(32768), 256, 0, stream>>>(S);
  // O[b] = P[b] @ Vt[b]^T + bv
  gemm8<1,0><<<dim3(256), 512, 0, stream>>>(S, Vt, O, bv, 1.f,
      32, 2048LL * 2048, 1024LL * 2048, 2048LL * 1024, 2048, 2048, 1024, 8, 32, 2);
  // out = O @ Wo + bo (fp32 out)
  gemm8<1,1><<<dim3(256), 512, 0, stream>>>(O, Wot, out, bo, 1.f,
      16, 0, 0, 0, 1024, 1024, 1024, 128, 512, 2);
}